// Round 3
// baseline (1553.583 us; speedup 1.0000x reference)
//
#include <hip/hip_runtime.h>
#include <math.h>

typedef __bf16 bf16;
typedef __attribute__((ext_vector_type(8))) __bf16 bf16x8;
typedef __attribute__((ext_vector_type(4))) __bf16 bf16x4;
typedef __attribute__((ext_vector_type(4))) float f32x4;

#define S_LEN 2048
#define HID_DIM 4096
#define N_HEADS 32
#define N_KV 8
#define HEAD_DIM 128

// ---------------- fp32 -> bf16 convert (4 elems/thread) ----------------
__global__ __launch_bounds__(256) void cvt_kernel(const float* __restrict__ in,
                                                  bf16* __restrict__ out) {
  int i = blockIdx.x * 256 + threadIdx.x;
  float4 v = reinterpret_cast<const float4*>(in)[i];
  bf16x4 o = {(bf16)v.x, (bf16)v.y, (bf16)v.z, (bf16)v.w};
  reinterpret_cast<bf16x4*>(out)[i] = o;
}

// ---------------- NT GEMM: C[m][n] = sum_k A[m][k] * B[n][k] ----------------
// A: M x K row-major (bf16), B: N x K row-major (bf16), C: M x N (OUT)
// 128x128 tile, BK=64, 256 threads (4 waves, 2x2 of 64x64)
template <typename OUT>
__global__ __launch_bounds__(256, 2) void gemm_nt(const bf16* __restrict__ A,
                                                  const bf16* __restrict__ B,
                                                  OUT* __restrict__ C,
                                                  int N, int K) {
  __shared__ bf16 As[128 * 64];
  __shared__ bf16 Bs[128 * 64];
  const int tid = threadIdx.x;
  const int lane = tid & 63;
  const int w = tid >> 6;
  const int g = lane >> 4, lr = lane & 15;
  const int wm = (w >> 1) * 64, wn = (w & 1) * 64;
  const int bm = blockIdx.y * 128, bn = blockIdx.x * 128;

  const bf16* Abase = A + (size_t)bm * K;
  const bf16* Bbase = B + (size_t)bn * K;

  const int s_row = (tid * 16) >> 7;    // 0..31 (rows advance by 32 per iter)
  const int s_colb = (tid * 16) & 127;  // byte offset within 128B row

  f32x4 acc[4][4] = {};
  uint4 ra[4], rb[4];

  auto gload = [&](uint4* dst, const bf16* base, int k0) {
#pragma unroll
    for (int it = 0; it < 4; ++it) {
      int row = s_row + it * 32;
      dst[it] = *reinterpret_cast<const uint4*>(base + (size_t)row * K + k0 +
                                                (s_colb >> 1));
    }
  };

  gload(ra, Abase, 0);
  gload(rb, Bbase, 0);

  const int nk = K >> 6;
  for (int kt = 0; kt < nk; ++kt) {
    __syncthreads();
#pragma unroll
    for (int it = 0; it < 4; ++it) {
      int row = s_row + it * 32;
      int off = (row * 128 + s_colb) ^ ((row & 7) << 4);
      *reinterpret_cast<uint4*>(reinterpret_cast<char*>(As) + off) = ra[it];
      *reinterpret_cast<uint4*>(reinterpret_cast<char*>(Bs) + off) = rb[it];
    }
    __syncthreads();
    if (kt + 1 < nk) {  // prefetch next tile's global loads over MFMA phase
      gload(ra, Abase, (kt + 1) << 6);
      gload(rb, Bbase, (kt + 1) << 6);
    }
#pragma unroll
    for (int ks = 0; ks < 2; ++ks) {
      bf16x8 af[4], bfr[4];
#pragma unroll
      for (int mi = 0; mi < 4; ++mi) {
        int row = wm + mi * 16 + lr;
        int off = (row * 128 + ks * 64 + g * 16) ^ ((row & 7) << 4);
        af[mi] = *reinterpret_cast<const bf16x8*>(
            reinterpret_cast<const char*>(As) + off);
      }
#pragma unroll
      for (int ni = 0; ni < 4; ++ni) {
        int row = wn + ni * 16 + lr;
        int off = (row * 128 + ks * 64 + g * 16) ^ ((row & 7) << 4);
        bfr[ni] = *reinterpret_cast<const bf16x8*>(
            reinterpret_cast<const char*>(Bs) + off);
      }
#pragma unroll
      for (int mi = 0; mi < 4; ++mi)
#pragma unroll
        for (int ni = 0; ni < 4; ++ni)
          acc[mi][ni] = __builtin_amdgcn_mfma_f32_16x16x32_bf16(
              af[mi], bfr[ni], acc[mi][ni], 0, 0, 0);
    }
  }

#pragma unroll
  for (int mi = 0; mi < 4; ++mi)
#pragma unroll
    for (int ni = 0; ni < 4; ++ni)
#pragma unroll
      for (int r = 0; r < 4; ++r) {
        int row = bm + wm + mi * 16 + g * 4 + r;
        int col = bn + wn + ni * 16 + lr;
        C[(size_t)row * N + col] = (OUT)acc[mi][ni][r];
      }
}

// ---------------- RoPE in-place on (S, heads*128) bf16 ----------------
__global__ __launch_bounds__(256) void rope_kernel(bf16* __restrict__ X,
                                                   int heads) {
  int idx = blockIdx.x * 256 + threadIdx.x;  // total S*heads*64
  int d = idx & 63;
  int h = (idx >> 6) % heads;
  int s = idx / (64 * heads);
  size_t base = (size_t)(s * heads + h) * 128;
  float x1 = (float)X[base + d];
  float x2 = (float)X[base + d + 64];
  // inv_freq = 10000^(-d/64) ; ln(10000)/64 = 0.14391156831212787
  float inv = __expf((float)d * -0.14391156831212787f);
  float f = (float)s * inv;
  float sv, cv;
  sincosf(f, &sv, &cv);
  X[base + d] = (bf16)(x1 * cv - x2 * sv);
  X[base + d + 64] = (bf16)(x2 * cv + x1 * sv);
}

// ---------------- V transpose: Vt[c][s] = V[s][c], c = kv*128+d ----------------
__global__ __launch_bounds__(256) void transpose_v(const bf16* __restrict__ V,
                                                   bf16* __restrict__ Vt) {
  int idx = blockIdx.x * 256 + threadIdx.x;  // total 2048*1024
  int s = idx & (S_LEN - 1);
  int c = idx >> 11;
  Vt[(size_t)c * S_LEN + s] = V[(size_t)s * (N_KV * HEAD_DIM) + c];
}

// ---------------- Flash attention (causal, GQA) ----------------
// grid (S/64, NH); block 256 = 4 waves x 16 q-rows.
// Q: (S, 4096) bf16 (post-RoPE); K: (S, 1024) bf16 (post-RoPE);
// Vt: (1024, S) bf16; O: (S, 4096) bf16.
__global__ __launch_bounds__(256, 2) void attn_kernel(const bf16* __restrict__ Q,
                                                      const bf16* __restrict__ K,
                                                      const bf16* __restrict__ Vt,
                                                      bf16* __restrict__ O) {
  __shared__ bf16 Ks[64 * 128];    // [key][d], 256B rows, swizzled
  __shared__ bf16 Vs[128 * 64];    // [d][key], 128B rows, swizzled
  __shared__ bf16 Ps[4][16 * 64];  // per-wave P, 128B rows, swizzled

  const int tid = threadIdx.x, lane = tid & 63, w = tid >> 6;
  const int g = lane >> 4, lr = lane & 15;
  const int qt = blockIdx.x, h = blockIdx.y;
  const int kvh = h >> 2;  // GROUPS = 4
  const int q0 = qt * 64;
  const int qrow = q0 + w * 16;

  // hoist Q fragments (A-frag: row = lr, k = ks*32 + g*8 .. +8)
  bf16x8 qf[4];
#pragma unroll
  for (int ks = 0; ks < 4; ++ks)
    qf[ks] = *reinterpret_cast<const bf16x8*>(
        Q + (size_t)(qrow + lr) * HID_DIM + h * HEAD_DIM + ks * 32 + g * 8);

  f32x4 o[8] = {};
  float m[4], l[4];
#pragma unroll
  for (int r = 0; r < 4; ++r) {
    m[r] = -INFINITY;
    l[r] = 0.f;
  }

  const int f0 = tid * 16;
  const float scale = 0.08838834764831845f;  // 1/sqrt(128)

  for (int kt = 0; kt <= qt; ++kt) {
    __syncthreads();
    // stage K tile (64x128) and Vt tile (128x64), both XOR-swizzled
#pragma unroll
    for (int it = 0; it < 4; ++it) {
      int f = f0 + it * 4096;
      {
        int row = f >> 8, colb = f & 255;
        uint4 v = *reinterpret_cast<const uint4*>(
            K + (size_t)(kt * 64 + row) * (N_KV * HEAD_DIM) + kvh * HEAD_DIM +
            (colb >> 1));
        int off = f ^ ((row & 7) << 4);
        *reinterpret_cast<uint4*>(reinterpret_cast<char*>(Ks) + off) = v;
      }
      {
        int row = f >> 7, colb = f & 127;
        uint4 v = *reinterpret_cast<const uint4*>(
            Vt + (size_t)(kvh * HEAD_DIM + row) * S_LEN + kt * 64 +
            (colb >> 1));
        int off = f ^ ((row & 7) << 4);
        *reinterpret_cast<uint4*>(reinterpret_cast<char*>(Vs) + off) = v;
      }
    }
    __syncthreads();

    // QK^T: 16x64 scores per wave
    f32x4 sc[4] = {};
#pragma unroll
    for (int ks = 0; ks < 4; ++ks) {
#pragma unroll
      for (int ni = 0; ni < 4; ++ni) {
        int row = ni * 16 + lr;
        int off = (row * 256 + ks * 64 + g * 16) ^ ((row & 7) << 4);
        bf16x8 kf = *reinterpret_cast<const bf16x8*>(
            reinterpret_cast<const char*>(Ks) + off);
        sc[ni] = __builtin_amdgcn_mfma_f32_16x16x32_bf16(qf[ks], kf, sc[ni],
                                                         0, 0, 0);
      }
    }

    // scale + causal mask
    const bool last = (kt == qt);
#pragma unroll
    for (int ni = 0; ni < 4; ++ni)
#pragma unroll
      for (int r = 0; r < 4; ++r) {
        float v = sc[ni][r] * scale;
        if (last) {
          int kk = kt * 64 + ni * 16 + lr;
          int qq = q0 + w * 16 + g * 4 + r;
          if (kk > qq) v = -1e9f;
        }
        sc[ni][r] = v;
      }

    // online softmax (row r lives across the 16 lanes sharing g)
#pragma unroll
    for (int r = 0; r < 4; ++r) {
      float rm = fmaxf(fmaxf(sc[0][r], sc[1][r]), fmaxf(sc[2][r], sc[3][r]));
#pragma unroll
      for (int sft = 1; sft < 16; sft <<= 1)
        rm = fmaxf(rm, __shfl_xor(rm, sft, 64));
      float mnew = fmaxf(m[r], rm);
      float corr = __expf(m[r] - mnew);
      float rs = 0.f;
#pragma unroll
      for (int ni = 0; ni < 4; ++ni) {
        float p = __expf(sc[ni][r] - mnew);
        sc[ni][r] = p;
        rs += p;
      }
#pragma unroll
      for (int sft = 1; sft < 16; sft <<= 1) rs += __shfl_xor(rs, sft, 64);
      l[r] = l[r] * corr + rs;
      m[r] = mnew;
#pragma unroll
      for (int nd = 0; nd < 8; ++nd) o[nd][r] *= corr;
    }

    // P -> LDS (bf16, swizzled), re-layout for MFMA A-fragment
#pragma unroll
    for (int ni = 0; ni < 4; ++ni)
#pragma unroll
      for (int r = 0; r < 4; ++r) {
        int row = g * 4 + r;
        int off = (row * 128 + (ni * 16 + lr) * 2) ^ ((row & 7) << 4);
        *reinterpret_cast<bf16*>(reinterpret_cast<char*>(Ps[w]) + off) =
            (bf16)sc[ni][r];
      }
    __syncthreads();

    // PV: O(16x128) += P(16x64) @ V(64x128)
#pragma unroll
    for (int ks = 0; ks < 2; ++ks) {
      int poff = (lr * 128 + ks * 64 + g * 16) ^ ((lr & 7) << 4);
      bf16x8 pf = *reinterpret_cast<const bf16x8*>(
          reinterpret_cast<const char*>(Ps[w]) + poff);
#pragma unroll
      for (int nd = 0; nd < 8; ++nd) {
        int row = nd * 16 + lr;
        int off = (row * 128 + ks * 64 + g * 16) ^ ((row & 7) << 4);
        bf16x8 vf = *reinterpret_cast<const bf16x8*>(
            reinterpret_cast<const char*>(Vs) + off);
        o[nd] = __builtin_amdgcn_mfma_f32_16x16x32_bf16(pf, vf, o[nd], 0, 0, 0);
      }
    }
  }

  // epilogue
#pragma unroll
  for (int nd = 0; nd < 8; ++nd)
#pragma unroll
    for (int r = 0; r < 4; ++r) {
      int row = q0 + w * 16 + g * 4 + r;
      int col = h * HEAD_DIM + nd * 16 + lr;
      O[(size_t)row * HID_DIM + col] = (bf16)(o[nd][r] / l[r]);
    }
}

// ---------------- launch ----------------
extern "C" void kernel_launch(void* const* d_in, const int* in_sizes, int n_in,
                              void* d_out, int out_size, void* d_ws,
                              size_t ws_size, hipStream_t stream) {
  const float* hs = (const float*)d_in[0];
  const float* Wq = (const float*)d_in[1];
  const float* Wk = (const float*)d_in[2];
  const float* Wv = (const float*)d_in[3];
  const float* Wo = (const float*)d_in[4];
  float* out = (float*)d_out;

  char* ws = (char*)d_ws;
  bf16* hb = (bf16*)(ws + 0);          // 16,777,216 B  (hidden bf16; later AO)
  bf16* Wqb = (bf16*)(ws + 16777216);  // 33,554,432 B  (Wq bf16; later Wo)
  bf16* Wkb = (bf16*)(ws + 50331648);  // 8,388,608 B
  bf16* Wvb = (bf16*)(ws + 58720256);  // 8,388,608 B
  bf16* Qb = (bf16*)(ws + 67108864);   // 16,777,216 B
  bf16* Kb = (bf16*)(ws + 83886080);   // 4,194,304 B
  bf16* Vb = (bf16*)(ws + 88080384);   // 4,194,304 B
  bf16* Vtb = (bf16*)(ws + 92274688);  // 4,194,304 B  -> total 96,468,992 B
  bf16* AOb = hb;                      // alias: hidden not needed after QKV
  bf16* Wob = Wqb;                     // alias: Wq not needed after Q GEMM

  // converts
  cvt_kernel<<<8192, 256, 0, stream>>>(hs, hb);     // 8,388,608 / 1024
  cvt_kernel<<<16384, 256, 0, stream>>>(Wq, Wqb);   // 16,777,216 / 1024
  cvt_kernel<<<4096, 256, 0, stream>>>(Wk, Wkb);
  cvt_kernel<<<4096, 256, 0, stream>>>(Wv, Wvb);

  // projections
  gemm_nt<bf16><<<dim3(32, 16), 256, 0, stream>>>(hb, Wqb, Qb, 4096, 4096);
  gemm_nt<bf16><<<dim3(8, 16), 256, 0, stream>>>(hb, Wkb, Kb, 1024, 4096);
  gemm_nt<bf16><<<dim3(8, 16), 256, 0, stream>>>(hb, Wvb, Vb, 1024, 4096);

  // Wo convert (after Q GEMM released Wqb)
  cvt_kernel<<<16384, 256, 0, stream>>>(Wo, Wob);

  // RoPE + V transpose
  rope_kernel<<<16384, 256, 0, stream>>>(Qb, N_HEADS);  // 2048*32*64 / 256
  rope_kernel<<<4096, 256, 0, stream>>>(Kb, N_KV);      // 2048*8*64 / 256
  transpose_v<<<8192, 256, 0, stream>>>(Vb, Vtb);       // 2048*1024 / 256

  // attention
  attn_kernel<<<dim3(32, 32), 256, 0, stream>>>(Qb, Kb, Vtb, AOb);

  // output projection (fp32 out)
  gemm_nt<float><<<dim3(32, 16), 256, 0, stream>>>(AOb, Wob, out, 4096, 4096);

  (void)in_sizes; (void)n_in; (void)out_size; (void)ws_size;
}